// Round 9
// baseline (227.681 us; speedup 1.0000x reference)
//
#include <hip/hip_runtime.h>

// Cumulative product along last dim of (4096, 32768) fp32.
// ONE WAVE PER ROW; 128 chunks of 256 elems (64 lanes x float4, 1KB
// coalesced per vmem op); 4-deep register ring prefetch; pure-VALU DPP
// wave scan (row_shr 1/2/4/8 + row_bcast15/31 + wave_shr1 + readlane).
// vs R7 (215.7us): stores are PLAIN (L2 write-back ack path, like the
// 6.8TB/s fill kernel); loads stay nontemporal. Single-variable test of
// the nt-store hint. PF=8 regressed (R8), so PF=4 retained.

#define COLS   32768
#define TPB    256
#define WPB    (TPB / 64)        // 4 waves (rows) per block
#define CHUNK  256               // elems per chunk: 64 lanes * 4
#define NCHUNK (COLS / CHUNK)    // 128
#define PF     4                 // prefetch depth in chunks

typedef float f32x4 __attribute__((ext_vector_type(4)));

#define ONE_BITS 0x3f800000      // 1.0f as int (multiplicative identity)

// x * dpp_moved(x); masked-off/invalid lanes contribute 1.0f.
template <int CTRL, int RM, int BM>
__device__ __forceinline__ float mul_dpp(float x) {
    int s = __builtin_amdgcn_update_dpp(ONE_BITS, __float_as_int(x),
                                        CTRL, RM, BM, false);
    return x * __int_as_float(s);
}

__global__ __launch_bounds__(TPB) void cumprod_rows(const float* __restrict__ x,
                                                    float* __restrict__ out) {
    const int lane = threadIdx.x & 63;
    const int wid  = threadIdx.x >> 6;
    const int row  = blockIdx.x * WPB + wid;

    const size_t base = (size_t)row * (size_t)COLS + (size_t)lane * 4;
    const float* px = x + base;
    float*       po = out + base;

    // ---- prime the prefetch ring (static indices only) ----
    f32x4 buf[PF];
    #pragma unroll
    for (int j = 0; j < PF; ++j)
        buf[j] = __builtin_nontemporal_load(
            reinterpret_cast<const f32x4*>(px + j * CHUNK));

    float carry = 1.0f;

    for (int cc = 0; cc < NCHUNK; cc += PF) {
        #pragma unroll
        for (int j = 0; j < PF; ++j) {
            f32x4 v = buf[j];

            // refill this ring slot from PF chunks ahead (uniform branch)
            const int nc = cc + PF + j;
            if (nc < NCHUNK)
                buf[j] = __builtin_nontemporal_load(
                    reinterpret_cast<const f32x4*>(px + nc * CHUNK));

            // in-lane inclusive scan of 4 elements
            v[1] *= v[0];
            v[2] *= v[1];
            v[3] *= v[2];

            // ---- wave-wide inclusive scan, pure VALU DPP ----
            float t = v[3];
            t = mul_dpp<0x111, 0xf, 0xf>(t);   // row_shr:1
            t = mul_dpp<0x112, 0xf, 0xf>(t);   // row_shr:2
            t = mul_dpp<0x114, 0xf, 0xf>(t);   // row_shr:4
            t = mul_dpp<0x118, 0xf, 0xf>(t);   // row_shr:8  (rows of 16 done)
            t = mul_dpp<0x142, 0xa, 0xf>(t);   // row_bcast:15 -> rows 1,3
            t = mul_dpp<0x143, 0xc, 0xf>(t);   // row_bcast:31 -> rows 2,3

            // exclusive prefix: lane i <- t[i-1], lane 0 <- 1.0 (wave_shr:1)
            float ex = __int_as_float(__builtin_amdgcn_update_dpp(
                ONE_BITS, __float_as_int(t), 0x138, 0xf, 0xf, false));

            const float m = carry * ex;

            // wave total (lane 63) -> next carry; uniform SGPR multiply
            carry *= __int_as_float(
                __builtin_amdgcn_readlane(__float_as_int(t), 63));

            f32x4 o;
            o[0] = v[0] * m;
            o[1] = v[1] * m;
            o[2] = v[2] * m;
            o[3] = v[3] * m;
            *reinterpret_cast<f32x4*>(po + (cc + j) * CHUNK) = o;   // plain store
        }
    }
}

extern "C" void kernel_launch(void* const* d_in, const int* in_sizes, int n_in,
                              void* d_out, int out_size, void* d_ws, size_t ws_size,
                              hipStream_t stream) {
    const float* x = (const float*)d_in[0];
    float* out = (float*)d_out;
    const int rows = out_size / COLS;          // 4096
    cumprod_rows<<<rows / WPB, TPB, 0, stream>>>(x, out);
}

// Round 10
// 212.520 us; speedup vs baseline: 1.0713x; 1.0713x over previous
//
#include <hip/hip_runtime.h>

// Cumulative product along last dim of (4096, 32768) fp32.
// ONE WAVE PER ROW; nt loads/stores; pure-VALU DPP wave scan.
// vs R7 (215.7us): chunks processed in PAIRS. Memory pattern is
// byte-identical to R7 (same 1KB coalesced nt loads/stores, same ring
// depth = 4 chunks in flight), but the two chunks' scan chains are
// independent -> 2x ILP on the dependent DPP sequence, half the loop
// iterations. Pair linked by scalar fix-up: mB = carry*TA*exB.

#define COLS   32768
#define TPB    256
#define WPB    (TPB / 64)          // 4 waves (rows) per block
#define CHUNK  256                 // elems per chunk: 64 lanes * 4
#define NPAIR  (COLS / (2 * CHUNK))  // 64 pairs per row
#define PFP    2                   // prefetch depth in pairs (= 4 chunks)

typedef float f32x4 __attribute__((ext_vector_type(4)));

#define ONE_BITS 0x3f800000        // 1.0f as int (multiplicative identity)

// x * dpp_moved(x); masked-off/invalid lanes contribute 1.0f.
template <int CTRL, int RM, int BM>
__device__ __forceinline__ float mul_dpp(float x) {
    int s = __builtin_amdgcn_update_dpp(ONE_BITS, __float_as_int(x),
                                        CTRL, RM, BM, false);
    return x * __int_as_float(s);
}

// full 64-lane inclusive-scan chain on t (6 DPP steps)
__device__ __forceinline__ float wave_scan(float t) {
    t = mul_dpp<0x111, 0xf, 0xf>(t);   // row_shr:1
    t = mul_dpp<0x112, 0xf, 0xf>(t);   // row_shr:2
    t = mul_dpp<0x114, 0xf, 0xf>(t);   // row_shr:4
    t = mul_dpp<0x118, 0xf, 0xf>(t);   // row_shr:8
    t = mul_dpp<0x142, 0xa, 0xf>(t);   // row_bcast:15 -> rows 1,3
    t = mul_dpp<0x143, 0xc, 0xf>(t);   // row_bcast:31 -> rows 2,3
    return t;
}

// exclusive shift: lane i <- t[i-1], lane 0 <- 1.0 (wave_shr:1)
__device__ __forceinline__ float excl(float t) {
    return __int_as_float(__builtin_amdgcn_update_dpp(
        ONE_BITS, __float_as_int(t), 0x138, 0xf, 0xf, false));
}

__global__ __launch_bounds__(TPB) void cumprod_rows(const float* __restrict__ x,
                                                    float* __restrict__ out) {
    const int lane = threadIdx.x & 63;
    const int wid  = threadIdx.x >> 6;
    const int row  = blockIdx.x * WPB + wid;

    const size_t base = (size_t)row * (size_t)COLS + (size_t)lane * 4;
    const float* px = x + base;
    float*       po = out + base;

    // ---- prime the prefetch ring: 2 pairs = 4 chunks (static indices) ----
    f32x4 buf[PFP][2];
    #pragma unroll
    for (int j = 0; j < PFP; ++j) {
        buf[j][0] = __builtin_nontemporal_load(
            reinterpret_cast<const f32x4*>(px + (2 * j)     * CHUNK));
        buf[j][1] = __builtin_nontemporal_load(
            reinterpret_cast<const f32x4*>(px + (2 * j + 1) * CHUNK));
    }

    float carry = 1.0f;

    for (int p = 0; p < NPAIR; p += PFP) {
        #pragma unroll
        for (int j = 0; j < PFP; ++j) {
            f32x4 vA = buf[j][0];
            f32x4 vB = buf[j][1];

            // refill this ring slot from PFP pairs ahead (uniform branch)
            const int np = p + j + PFP;
            if (np < NPAIR) {
                buf[j][0] = __builtin_nontemporal_load(
                    reinterpret_cast<const f32x4*>(px + (2 * np)     * CHUNK));
                buf[j][1] = __builtin_nontemporal_load(
                    reinterpret_cast<const f32x4*>(px + (2 * np + 1) * CHUNK));
            }

            // two independent in-lane scans (ILP x2)
            vA[1] *= vA[0]; vB[1] *= vB[0];
            vA[2] *= vA[1]; vB[2] *= vB[1];
            vA[3] *= vA[2]; vB[3] *= vB[2];

            // two independent DPP wave scans (chains interleave)
            float tA = wave_scan(vA[3]);
            float tB = wave_scan(vB[3]);
            float exA = excl(tA);
            float exB = excl(tB);

            // scalar pair link
            float TA = __int_as_float(
                __builtin_amdgcn_readlane(__float_as_int(tA), 63));
            float TB = __int_as_float(
                __builtin_amdgcn_readlane(__float_as_int(tB), 63));
            const float mA = carry * exA;
            const float cA = carry * TA;     // inclusive through chunk A
            const float mB = cA * exB;
            carry = cA * TB;

            f32x4 oA, oB;
            oA[0] = vA[0] * mA; oB[0] = vB[0] * mB;
            oA[1] = vA[1] * mA; oB[1] = vB[1] * mB;
            oA[2] = vA[2] * mA; oB[2] = vB[2] * mB;
            oA[3] = vA[3] * mA; oB[3] = vB[3] * mB;
            __builtin_nontemporal_store(oA,
                reinterpret_cast<f32x4*>(po + (2 * (p + j))     * CHUNK));
            __builtin_nontemporal_store(oB,
                reinterpret_cast<f32x4*>(po + (2 * (p + j) + 1) * CHUNK));
        }
    }
}

extern "C" void kernel_launch(void* const* d_in, const int* in_sizes, int n_in,
                              void* d_out, int out_size, void* d_ws, size_t ws_size,
                              hipStream_t stream) {
    const float* x = (const float*)d_in[0];
    float* out = (float*)d_out;
    const int rows = out_size / COLS;          // 4096
    cumprod_rows<<<rows / WPB, TPB, 0, stream>>>(x, out);
}